// Round 2
// baseline (1405.934 us; speedup 1.0000x reference)
//
#include <hip/hip_runtime.h>

#define D    128
#define CAP  256            // rows cached in LDS (128 KB)
#define BLK  1024           // threads per block = 16 waves
#define RPI  32             // rows per iteration (BLK/32)

// Kernel 1: segment bounds. bounds[s] = lower_bound(batch, s), s in [0, B].
__global__ void seg_bounds_kernel(const int* __restrict__ batch,
                                  int* __restrict__ bounds, int N, int B)
{
    int s = blockIdx.x * blockDim.x + threadIdx.x;
    if (s > B) return;
    int lo = 0, hi = N;
    while (lo < hi) { int m = (lo + hi) >> 1; if (batch[m] < s) lo = m + 1; else hi = m; }
    bounds[s] = lo;
}

// Kernel 2: one block (1024 thr) per segment, single HBM read of x.
// Pass A: stream rows -> column sums; cache rows < CAP in LDS.
// Pass B: att_i = <x_i, cmean> (rows from LDS), accumulate att_i * x_i.
// Epilogue: out[s] = pmean @ W^T + bias.
__global__ __launch_bounds__(BLK) void attnpool_kernel(
    const float* __restrict__ x, const int* __restrict__ bounds,
    const float* __restrict__ W, const float* __restrict__ bias,
    float* __restrict__ out)
{
    __shared__ __align__(16) float cache[CAP * D];   // 131072 B
    __shared__ float red[16][D];                     //   8192 B
    __shared__ float cmean[D];                       //    512 B
    __shared__ float pmean[D];                       //    512 B

    const int s    = blockIdx.x;
    const int tid  = threadIdx.x;
    const int slot = tid >> 5;          // 0..31 : row slot
    const int q    = tid & 31;          // float4 index within row
    const int wave = tid >> 6;          // 0..15

    const int start = bounds[s];
    const int end   = bounds[s + 1];
    const int n     = end - start;
    const float inv_n = (n > 0) ? (1.0f / (float)n) : 0.0f;

    const float4* x4 = (const float4*)x;
    float4*       c4 = (float4*)cache;

    // ---------------- Pass A: column sums + LDS fill ----------------
    float a0 = 0.f, a1 = 0.f, a2 = 0.f, a3 = 0.f;
    for (int r = start + slot; r < end; r += RPI) {
        float4 v = x4[(long)r * 32 + q];
        a0 += v.x; a1 += v.y; a2 += v.z; a3 += v.w;
        int cr = r - start;
        if (cr < CAP) c4[cr * 32 + q] = v;
    }
    // combine the two half-waves (same columns, disjoint rows)
    a0 += __shfl_xor(a0, 32);
    a1 += __shfl_xor(a1, 32);
    a2 += __shfl_xor(a2, 32);
    a3 += __shfl_xor(a3, 32);
    if ((tid & 32) == 0) {
        red[wave][q * 4 + 0] = a0;
        red[wave][q * 4 + 1] = a1;
        red[wave][q * 4 + 2] = a2;
        red[wave][q * 4 + 3] = a3;
    }
    __syncthreads();
    if (tid < D) {
        float t = 0.f;
        #pragma unroll
        for (int i = 0; i < 16; ++i) t += red[i][tid];
        cmean[tid] = t * inv_n;
    }
    __syncthreads();

    // ---------------- Pass B: att-weighted column sums (LDS-sourced) ----------------
    float p0 = 0.f, p1 = 0.f, p2 = 0.f, p3 = 0.f;
    {
        const float4 cm = ((const float4*)cmean)[q];
        for (int r = start + slot; r < end; r += RPI) {
            const int cr = r - start;
            float4 v;
            if (cr < CAP) v = c4[cr * 32 + q];
            else          v = x4[(long)r * 32 + q];   // rare overflow; L2-warm
            float part = v.x * cm.x + v.y * cm.y + v.z * cm.z + v.w * cm.w;
            part += __shfl_xor(part, 1);
            part += __shfl_xor(part, 2);
            part += __shfl_xor(part, 4);
            part += __shfl_xor(part, 8);
            part += __shfl_xor(part, 16);
            p0 += part * v.x; p1 += part * v.y; p2 += part * v.z; p3 += part * v.w;
        }
    }
    p0 += __shfl_xor(p0, 32);
    p1 += __shfl_xor(p1, 32);
    p2 += __shfl_xor(p2, 32);
    p3 += __shfl_xor(p3, 32);
    __syncthreads();                     // red[] reuse
    if ((tid & 32) == 0) {
        red[wave][q * 4 + 0] = p0;
        red[wave][q * 4 + 1] = p1;
        red[wave][q * 4 + 2] = p2;
        red[wave][q * 4 + 3] = p3;
    }
    __syncthreads();
    if (tid < D) {
        float t = 0.f;
        #pragma unroll
        for (int i = 0; i < 16; ++i) t += red[i][tid];
        pmean[tid] = t * inv_n;
    }
    __syncthreads();

    // ---------------- Epilogue: out[s] = pmean @ W^T + bias ----------------
    {
        const float4* W4 = (const float4*)W;
        const float4  pm = ((const float4*)pmean)[q];
        #pragma unroll
        for (int j = slot; j < D; j += RPI) {
            float4 w = W4[j * 32 + q];
            float part = w.x * pm.x + w.y * pm.y + w.z * pm.z + w.w * pm.w;
            part += __shfl_xor(part, 1);
            part += __shfl_xor(part, 2);
            part += __shfl_xor(part, 4);
            part += __shfl_xor(part, 8);
            part += __shfl_xor(part, 16);
            if (q == 0) out[(long)s * D + j] = part + bias[j];
        }
    }
}

extern "C" void kernel_launch(void* const* d_in, const int* in_sizes, int n_in,
                              void* d_out, int out_size, void* d_ws, size_t ws_size,
                              hipStream_t stream) {
    const float* x     = (const float*)d_in[0];
    const int*   batch = (const int*)d_in[1];
    const float* W     = (const float*)d_in[2];
    const float* bias  = (const float*)d_in[3];
    float*       out   = (float*)d_out;

    const int N = in_sizes[1];        // 2,000,000 rows
    const int B = out_size / D;       // 8192 segments
    int* bounds = (int*)d_ws;         // B+1 ints

    seg_bounds_kernel<<<(B + 1 + 255) / 256, 256, 0, stream>>>(batch, bounds, N, B);
    attnpool_kernel<<<B, BLK, 0, stream>>>(x, bounds, W, bias, out);
}